// Round 4
// baseline (506.452 us; speedup 1.0000x reference)
//
#include <hip/hip_runtime.h>
#include <hip/hip_fp16.h>
#include <math.h>

// ---------------------------------------------------------------------------
// GAT graph encoder: 2x GATConv (PyG semantics, add_self_loops=False)
// R8->R9: k_agg critical-path restructure. Edge ids broadcast via __shfl
//   (register) instead of LDS; feat gathers issued IMMEDIATELY after esrc
//   lands, BEFORE the asrc/exp alpha staging (whose latency now hides under
//   the feat loads). Batches of 16 edges software-pipelined (issue b+1
//   before consuming b). sj LDS removed. Raises each wave's gather duty
//   cycle; tests duty-cycle-bound vs fabric-service-ceiling hypothesis.
//   GEMM (R6) and CSR build (R5) unchanged.
// ---------------------------------------------------------------------------

typedef _Float16 f16x8 __attribute__((ext_vector_type(8)));
typedef float    f32x4 __attribute__((ext_vector_type(4)));

// ---------------- CSR build ----------------

__global__ __launch_bounds__(256) void k_hist(const int* __restrict__ dst,
                                              int* __restrict__ bcnt, int E, int NBUCK) {
    __shared__ int lh[1024];
    int t = threadIdx.x;
    for (int i = t; i < NBUCK; i += 256) lh[i] = 0;
    __syncthreads();
    for (int e = blockIdx.x * 256 + t; e < E; e += gridDim.x * 256)
        atomicAdd(&lh[dst[e] >> 7], 1);
    __syncthreads();
    for (int i = t; i < NBUCK; i += 256) {
        int c = lh[i];
        if (c) atomicAdd(&bcnt[i], c);
    }
}

__global__ void k_bscan(const int* __restrict__ bcnt, int* __restrict__ bbase,
                        int* __restrict__ bcur, int* __restrict__ off,
                        int NBUCK, int N, int E) {
    __shared__ int sd[1024];
    int t = threadIdx.x;
    int v = (t < NBUCK) ? bcnt[t] : 0;
    sd[t] = v; __syncthreads();
    for (int ofs = 1; ofs < 1024; ofs <<= 1) {
        int w = (t >= ofs) ? sd[t - ofs] : 0;
        __syncthreads();
        sd[t] += w;
        __syncthreads();
    }
    if (t < NBUCK) { int ex = sd[t] - v; bbase[t] = ex; bcur[t] = ex; }
    if (t == 0) { bbase[NBUCK] = E; off[N] = E; }
}

__global__ __launch_bounds__(256) void k_binscatter(
    const int* __restrict__ src, const int* __restrict__ dst,
    int* __restrict__ bcur, int* __restrict__ tmp, int E, int NBUCK) {
    __shared__ int lh[1024], lbase[1024];
    int t = threadIdx.x;
    for (int i = t; i < NBUCK; i += 256) lh[i] = 0;
    __syncthreads();
    int tbeg = blockIdx.x * 8192;
    int tend = tbeg + 8192; if (tend > E) tend = E;
    for (int e = tbeg + t; e < tend; e += 256) atomicAdd(&lh[dst[e] >> 7], 1);
    __syncthreads();
    for (int i = t; i < NBUCK; i += 256) {
        int c = lh[i];
        lbase[i] = c ? atomicAdd(&bcur[i], c) : 0;
        lh[i] = 0;
    }
    __syncthreads();
    for (int e = tbeg + t; e < tend; e += 256) {
        int d = dst[e];
        int b = d >> 7;
        int r = atomicAdd(&lh[b], 1);
        tmp[lbase[b] + r] = (src[e] << 7) | (d & 127);
    }
}

__global__ __launch_bounds__(256) void k_bsort(
    const int* __restrict__ tmp, const int* __restrict__ bbase,
    int* __restrict__ off, int* __restrict__ esrc, int N) {
    __shared__ int h[128], hs[128], cur[128];
    int b = blockIdx.x, t = threadIdx.x;
    int base = bbase[b];
    int cnt  = bbase[b + 1] - base;
    int node0 = b << 7;
    if (t < 128) h[t] = 0;
    __syncthreads();
    for (int i = t; i < cnt; i += 256) atomicAdd(&h[tmp[base + i] & 127], 1);
    __syncthreads();
    if (t < 128) hs[t] = h[t];
    __syncthreads();
    for (int ofs = 1; ofs < 128; ofs <<= 1) {
        int w = (t < 128 && t >= ofs) ? hs[t - ofs] : 0;
        __syncthreads();
        if (t < 128) hs[t] += w;
        __syncthreads();
    }
    if (t < 128) {
        int ex = hs[t] - h[t];
        if (node0 + t < N) off[node0 + t] = base + ex;
        cur[t] = base + ex;
    }
    __syncthreads();
    for (int i = t; i < cnt; i += 256) {
        int p = tmp[base + i];
        int pos = atomicAdd(&cur[p & 127], 1);
        esrc[pos] = p >> 7;
    }
}

// ---------------- MFMA GEMM + fused attention dots ----------------
// Y(fp16)[N,128] = cast16(X[N,128]) @ cast16(W[128,128]); fp32 accum.
// A-frag: m=lane&15 (row), k=(lane>>4)*8+j. B-frag: n=lane&15 (col), same k.
// C/D: col=lane&15, row=(lane>>4)*4+reg.

template <int H, typename TI>
__global__ __launch_bounds__(256, 2) void k_gemm_mfma(
    const TI* __restrict__ X, const float* __restrict__ Wg,
    const float* __restrict__ att_s, const float* __restrict__ att_d,
    __half* __restrict__ Y, float* __restrict__ as_, float* __restrict__ ad_, int N)
{
    __shared__ _Float16 Wh[128 * 128];   // [k][col]
    __shared__ _Float16 Xh[64][136];     // +8 pad: breaks 256B-stride bank clash
    const int t = threadIdx.x;
    const int lane = t & 63;
    const int wv = t >> 6;
    const int m = lane & 15;
    const int q = lane >> 4;

    // stage W fp32 -> fp16 (coalesced float4 reads)
    for (int i = t; i < 128 * 128 / 4; i += 256) {
        float4 w4 = ((const float4*)Wg)[i];
        _Float16* d = &Wh[i * 4];
        d[0] = (_Float16)w4.x; d[1] = (_Float16)w4.y;
        d[2] = (_Float16)w4.z; d[3] = (_Float16)w4.w;
    }
    __syncthreads();

    // preload all B fragments into registers (8 ntiles x 4 ksteps x 4 VGPR)
    f16x8 bfr[8][4];
#pragma unroll
    for (int nt = 0; nt < 8; nt++) {
#pragma unroll
        for (int ks = 0; ks < 4; ks++) {
            f16x8 b;
#pragma unroll
            for (int j = 0; j < 8; j++)
                b[j] = Wh[(ks * 32 + q * 8 + j) * 128 + nt * 16 + m];
            bfr[nt][ks] = b;
        }
    }
    float atts_v[8], attd_v[8];
#pragma unroll
    for (int nt = 0; nt < 8; nt++) {
        atts_v[nt] = att_s[nt * 16 + m];
        attd_v[nt] = att_d[nt * 16 + m];
    }

    for (int base = blockIdx.x * 64; base < N; base += gridDim.x * 64) {
        // stage 64 rows of X -> fp16 LDS (1024 chunks of 8 halfs, 4/thread)
        for (int i = t; i < 1024; i += 256) {
            int r = i >> 4, c8 = i & 15;
            int gr = base + r;
            _Float16* d = &Xh[r][c8 * 8];
            if (gr < N) {
                if constexpr (sizeof(TI) == 4) {
                    const float4* s = (const float4*)((const float*)X + (size_t)gr * 128 + c8 * 8);
                    float4 x0 = s[0], x1 = s[1];
                    d[0] = (_Float16)x0.x; d[1] = (_Float16)x0.y;
                    d[2] = (_Float16)x0.z; d[3] = (_Float16)x0.w;
                    d[4] = (_Float16)x1.x; d[5] = (_Float16)x1.y;
                    d[6] = (_Float16)x1.z; d[7] = (_Float16)x1.w;
                } else {
                    *(uint4*)d = *(const uint4*)((const __half*)X + (size_t)gr * 128 + c8 * 8);
                }
            } else {
                uint4 z; z.x = 0; z.y = 0; z.z = 0; z.w = 0;
                *(uint4*)d = z;
            }
        }
        __syncthreads();

        const int rowb = base + wv * 16;
        f32x4 acc[8];
#pragma unroll
        for (int nt = 0; nt < 8; nt++) { acc[nt][0] = 0.f; acc[nt][1] = 0.f; acc[nt][2] = 0.f; acc[nt][3] = 0.f; }
#pragma unroll
        for (int ks = 0; ks < 4; ks++) {
            f16x8 af = *(const f16x8*)&Xh[wv * 16 + m][ks * 32 + q * 8];
#pragma unroll
            for (int nt = 0; nt < 8; nt++)
                acc[nt] = __builtin_amdgcn_mfma_f32_16x16x32_f16(af, bfr[nt][ks], acc[nt], 0, 0, 0);
        }

        // Y writes (fp16 scalar stores; C-layout)
#pragma unroll
        for (int nt = 0; nt < 8; nt++) {
#pragma unroll
            for (int i = 0; i < 4; i++) {
                int r = rowb + q * 4 + i;
                if (r < N) Y[(size_t)r * 128 + nt * 16 + m] = __float2half(acc[nt][i]);
            }
        }

        // fused attention dots: per-lane partials, butterfly over the 16 cols
        if (H == 4) {
            float ph[4][4], pdv[4][4];
#pragma unroll
            for (int h = 0; h < 4; h++)
#pragma unroll
                for (int i = 0; i < 4; i++) {
                    ph[h][i]  = acc[2 * h][i] * atts_v[2 * h] + acc[2 * h + 1][i] * atts_v[2 * h + 1];
                    pdv[h][i] = acc[2 * h][i] * attd_v[2 * h] + acc[2 * h + 1][i] * attd_v[2 * h + 1];
                }
#pragma unroll
            for (int lvl = 0; lvl < 4; lvl++) {
                const int msk = 1 << lvl;
#pragma unroll
                for (int h = 0; h < 4; h++)
#pragma unroll
                    for (int i = 0; i < 4; i++) {
                        ph[h][i]  += __shfl_xor(ph[h][i], msk, 64);
                        pdv[h][i] += __shfl_xor(pdv[h][i], msk, 64);
                    }
            }
            if (m == 0) {
#pragma unroll
                for (int i = 0; i < 4; i++) {
                    int r = rowb + q * 4 + i;
                    if (r < N) {
#pragma unroll
                        for (int h = 0; h < 4; h++) {
                            as_[(size_t)r * 4 + h] = ph[h][i];
                            ad_[(size_t)r * 4 + h] = pdv[h][i];
                        }
                    }
                }
            }
        } else {
            float ps[4], pdv[4];
#pragma unroll
            for (int i = 0; i < 4; i++) {
                float s = 0.f, dsum = 0.f;
#pragma unroll
                for (int nt = 0; nt < 8; nt++) {
                    s    += acc[nt][i] * atts_v[nt];
                    dsum += acc[nt][i] * attd_v[nt];
                }
                ps[i] = s; pdv[i] = dsum;
            }
#pragma unroll
            for (int lvl = 0; lvl < 4; lvl++) {
                const int msk = 1 << lvl;
#pragma unroll
                for (int i = 0; i < 4; i++) {
                    ps[i]  += __shfl_xor(ps[i], msk, 64);
                    pdv[i] += __shfl_xor(pdv[i], msk, 64);
                }
            }
            if (m == 0) {
#pragma unroll
                for (int i = 0; i < 4; i++) {
                    int r = rowb + q * 4 + i;
                    if (r < N) { as_[r] = ps[i]; ad_[r] = pdv[i]; }
                }
            }
        }
        __syncthreads();   // protect Xh before next tile's staging
    }
}

// ---------------- aggregation: one wave per dst node ----------------
// R9: early-issue gather. Per 64-edge chunk: esrc lands -> __shfl broadcasts
// edge ids -> 4 uint4 feat loads issued immediately -> alpha staging
// (asrc gather + exp -> LDS) runs UNDER the feat latency -> consume.
// Batches of 16 edges pipelined: issue batch b+1 before consuming batch b.
// Tail slots weight 0 (no divergence). Cross-group reduce at node end.

template <int H, typename TO>
__global__ __launch_bounds__(256) void k_agg(
    const __half* __restrict__ feat,  // [N,128] fp16
    const float* __restrict__ asrc,   // [N,H]
    const float* __restrict__ adst,   // [N,H]
    const int*   __restrict__ off,    // [N+1]
    const int*   __restrict__ esrc,   // [E]
    const float* __restrict__ bias,   // [128]
    TO*          __restrict__ out,    // [N,128]
    int N)
{
    __shared__ __attribute__((aligned(16))) float sp[4][64 * H];  // head-major alphas

    int wave = threadIdx.x >> 6;
    int lane = threadIdx.x & 63;
    int node = (blockIdx.x * 256 + threadIdx.x) >> 6;
    if (node >= N) return;
    int beg = off[node], end = off[node + 1];

    float adst_i[H];
#pragma unroll
    for (int h = 0; h < H; h++) adst_i[h] = adst[(size_t)node * H + h];

    const int g    = lane >> 4;                    // edge sub-slot 0..3
    const int sub  = lane & 15;                    // col octet: cols sub*8..+7
    const int head = (H == 4) ? (sub >> 2) : 0;    // 32 cols per head
    const __half* fb = feat + sub * 8;

    float o[8];
#pragma unroll
    for (int k = 0; k < 8; k++) o[k] = 0.f;
    float ssum = 0.f;

    for (int cbeg = beg; cbeg < end; cbeg += 64) {
        int cnt = end - cbeg; if (cnt > 64) cnt = 64;

        // 1. edge ids (coalesced). Inactive lanes hold 0 (safe shfl source).
        int j = 0;
        if (lane < cnt) j = esrc[cbeg + lane];

        // 2. issue batch-0 feat gathers ASAP via register broadcast
        uint4 hv[4];
#pragma unroll
        for (int u = 0; u < 4; u++) {
            int jj = __shfl(j, 4 * u + g, 64);
            hv[u] = *(const uint4*)(fb + (size_t)jj * 128);
        }

        // 3. alpha staging — latency hides under the feat loads above
        if (lane < cnt) {
            if (H == 4) {
                float4 av = *(const float4*)(asrc + (size_t)j * 4);
                float e;
                e = av.x + adst_i[0]; e = e > 0.f ? e : 0.2f * e; sp[wave][0 * 64 + lane] = __expf(e);
                e = av.y + adst_i[1]; e = e > 0.f ? e : 0.2f * e; sp[wave][1 * 64 + lane] = __expf(e);
                e = av.z + adst_i[2]; e = e > 0.f ? e : 0.2f * e; sp[wave][2 * 64 + lane] = __expf(e);
                e = av.w + adst_i[3]; e = e > 0.f ? e : 0.2f * e; sp[wave][3 * 64 + lane] = __expf(e);
            } else {
                float e = asrc[j] + adst_i[0];
                e = e > 0.f ? e : 0.2f * e;
                sp[wave][lane] = __expf(e);
            }
        }
        asm volatile("s_waitcnt lgkmcnt(0)" ::: "memory");

        // 4. pipelined consume: issue batch b+1, then consume batch b
        const int nb = (cnt + 15) >> 4;
        for (int b = 0; b < nb; b++) {
            const int b0 = b << 4;
            float aa[4];
#pragma unroll
            for (int u = 0; u < 4; u++) {
                int e = b0 + 4 * u + g;
                aa[u] = (e < cnt) ? sp[wave][head * 64 + e] : 0.f;
            }
            uint4 nv[4];
            if (b + 1 < nb) {
#pragma unroll
                for (int u = 0; u < 4; u++) {
                    int jj = __shfl(j, b0 + 16 + 4 * u + g, 64);
                    nv[u] = *(const uint4*)(fb + (size_t)jj * 128);
                }
            }
#pragma unroll
            for (int u = 0; u < 4; u++) {
                const __half* hp = (const __half*)&hv[u];
                ssum += aa[u];
#pragma unroll
                for (int k = 0; k < 8; k++)
                    o[k] = fmaf(aa[u], __half2float(hp[k]), o[k]);
            }
            if (b + 1 < nb) {
#pragma unroll
                for (int u = 0; u < 4; u++) hv[u] = nv[u];
            }
        }
    }

    // reduce across the 4 edge-groups (lanes with equal sub share cols/head)
#pragma unroll
    for (int k = 0; k < 8; k++) {
        o[k] += __shfl_xor(o[k], 16, 64);
        o[k] += __shfl_xor(o[k], 32, 64);
    }
    ssum += __shfl_xor(ssum, 16, 64);
    ssum += __shfl_xor(ssum, 32, 64);

    if (g == 0) {
        float inv = 1.f / (ssum + 1e-16f);
        float r[8];
#pragma unroll
        for (int k = 0; k < 8; k++) {
            r[k] = o[k] * inv + bias[sub * 8 + k];
            r[k] = r[k] > 0.f ? r[k] : expm1f(r[k]);
        }
        if constexpr (sizeof(TO) == 2) {
            __half2 hh[4];
#pragma unroll
            for (int p = 0; p < 4; p++) hh[p] = __floats2half2_rn(r[2 * p], r[2 * p + 1]);
            *(uint4*)((__half*)out + (size_t)node * 128 + sub * 8) = *(const uint4*)hh;
        } else {
            float4 v0 = make_float4(r[0], r[1], r[2], r[3]);
            float4 v1 = make_float4(r[4], r[5], r[6], r[7]);
            *(float4*)((float*)out + (size_t)node * 128 + sub * 8)     = v0;
            *(float4*)((float*)out + (size_t)node * 128 + sub * 8 + 4) = v1;
        }
    }
}

// ---------------- launch ----------------

extern "C" void kernel_launch(void* const* d_in, const int* in_sizes, int n_in,
                              void* d_out, int out_size, void* d_ws, size_t ws_size,
                              hipStream_t stream)
{
    const float* x    = (const float*)d_in[0];
    const int*   a    = (const int*)  d_in[1];
    const float* W1   = (const float*)d_in[2];
    const float* as1w = (const float*)d_in[3];
    const float* ad1w = (const float*)d_in[4];
    const float* b1   = (const float*)d_in[5];
    const float* W2   = (const float*)d_in[6];
    const float* as2w = (const float*)d_in[7];
    const float* ad2w = (const float*)d_in[8];
    const float* b2   = (const float*)d_in[9];

    const int N = in_sizes[0] / 128;
    const int E = in_sizes[1] / 2;
    const int* srcA = a;
    const int* dstA = a + E;
    const int NBUCK = (N + 127) >> 7;

    char* ws = (char*)d_ws;
    size_t o = 0;
    auto alloc = [&](size_t bytes) -> void* {
        void* p = ws + o;
        o += (bytes + 255) & ~(size_t)255;
        return p;
    };
    __half* hbuf  = (__half*)alloc((size_t)N * 128 * 2);  // fp16 gather payload
    __half* hact  = (__half*)alloc((size_t)N * 128 * 2);  // elu(gat1) fp16, GEMM2 input
    float*  as1   = (float*) alloc((size_t)N * 4 * 4);
    float*  ad1   = (float*) alloc((size_t)N * 4 * 4);
    float*  as2   = (float*) alloc((size_t)N * 4);
    float*  ad2   = (float*) alloc((size_t)N * 4);
    int*    off   = (int*)   alloc((size_t)(N + 1) * 4);
    int*    esrc  = (int*)   alloc((size_t)E * 4);
    int*    tmp   = (int*)   alloc((size_t)E * 4);
    int*    bcnt  = (int*)   alloc(1024 * 4);
    int*    bbase = (int*)   alloc(1025 * 4);
    int*    bcur  = (int*)   alloc(1024 * 4);

    // CSR build (rebuilt each launch; ws is re-poisoned)
    hipMemsetAsync(bcnt, 0, (size_t)NBUCK * 4, stream);
    k_hist<<<256, 256, 0, stream>>>(dstA, bcnt, E, NBUCK);
    k_bscan<<<1, 1024, 0, stream>>>(bcnt, bbase, bcur, off, NBUCK, N, E);
    k_binscatter<<<(E + 8191) / 8192, 256, 0, stream>>>(srcA, dstA, bcur, tmp, E, NBUCK);
    k_bsort<<<NBUCK, 256, 0, stream>>>(tmp, bbase, off, esrc, N);

    // layer 1 (MFMA GEMM + fused attdot, fp16 Y)
    k_gemm_mfma<4, float><<<512, 256, 0, stream>>>(x, W1, as1w, ad1w, hbuf, as1, ad1, N);
    k_agg<4, __half><<<(N + 3) / 4, 256, 0, stream>>>(hbuf, as1, ad1, off, esrc, b1, hact, N);

    // layer 2
    k_gemm_mfma<1, __half><<<512, 256, 0, stream>>>(hact, W2, as2w, ad2w, hbuf, as2, ad2, N);
    k_agg<1, float><<<(N + 3) / 4, 256, 0, stream>>>(hbuf, as2, ad2, off, esrc, b2, (float*)d_out, N);
}

// Round 6
// 410.643 us; speedup vs baseline: 1.2333x; 1.2333x over previous
//
#include <hip/hip_runtime.h>
#include <hip/hip_fp16.h>
#include <math.h>

// ---------------------------------------------------------------------------
// GAT graph encoder: 2x GATConv (PyG semantics, add_self_loops=False)
// R9->R10 (resubmit; R10 bench never acquired a GPU): REVERT k_agg to R8
//   form (R9's __shfl broadcast = ds_bpermute chains + occupancy collapse
//   79->40%, k_agg 91.5->141us). k_agg gather concurrency is
//   HW-queue-limited (~2.8 TB/s beyond-L2 random 256B rows); accepted.
//   NEW: fuse k_hist into GEMM1 (independent work) with interleaved block
//   roles (bid%3==2 -> hist) so hist hides under GEMM1 and one launch
//   boundary disappears. Tests launch-overhead hypothesis for the ~150us
//   unaccounted remainder.
// ---------------------------------------------------------------------------

typedef _Float16 f16x8 __attribute__((ext_vector_type(8)));
typedef float    f32x4 __attribute__((ext_vector_type(4)));

// ---------------- CSR build ----------------

__device__ __forceinline__ void hist_body(const int* __restrict__ dst,
                                          int* __restrict__ bcnt, int E, int NBUCK,
                                          int hb, int hnb) {
    __shared__ int lh[1024];
    int t = threadIdx.x;
    for (int i = t; i < NBUCK; i += 256) lh[i] = 0;
    __syncthreads();
    for (int e = hb * 256 + t; e < E; e += hnb * 256)
        atomicAdd(&lh[dst[e] >> 7], 1);
    __syncthreads();
    for (int i = t; i < NBUCK; i += 256) {
        int c = lh[i];
        if (c) atomicAdd(&bcnt[i], c);
    }
}

__global__ void k_bscan(const int* __restrict__ bcnt, int* __restrict__ bbase,
                        int* __restrict__ bcur, int* __restrict__ off,
                        int NBUCK, int N, int E) {
    __shared__ int sd[1024];
    int t = threadIdx.x;
    int v = (t < NBUCK) ? bcnt[t] : 0;
    sd[t] = v; __syncthreads();
    for (int ofs = 1; ofs < 1024; ofs <<= 1) {
        int w = (t >= ofs) ? sd[t - ofs] : 0;
        __syncthreads();
        sd[t] += w;
        __syncthreads();
    }
    if (t < NBUCK) { int ex = sd[t] - v; bbase[t] = ex; bcur[t] = ex; }
    if (t == 0) { bbase[NBUCK] = E; off[N] = E; }
}

__global__ __launch_bounds__(256) void k_binscatter(
    const int* __restrict__ src, const int* __restrict__ dst,
    int* __restrict__ bcur, int* __restrict__ tmp, int E, int NBUCK) {
    __shared__ int lh[1024], lbase[1024];
    int t = threadIdx.x;
    for (int i = t; i < NBUCK; i += 256) lh[i] = 0;
    __syncthreads();
    int tbeg = blockIdx.x * 8192;
    int tend = tbeg + 8192; if (tend > E) tend = E;
    for (int e = tbeg + t; e < tend; e += 256) atomicAdd(&lh[dst[e] >> 7], 1);
    __syncthreads();
    for (int i = t; i < NBUCK; i += 256) {
        int c = lh[i];
        lbase[i] = c ? atomicAdd(&bcur[i], c) : 0;
        lh[i] = 0;
    }
    __syncthreads();
    for (int e = tbeg + t; e < tend; e += 256) {
        int d = dst[e];
        int b = d >> 7;
        int r = atomicAdd(&lh[b], 1);
        tmp[lbase[b] + r] = (src[e] << 7) | (d & 127);
    }
}

__global__ __launch_bounds__(256) void k_bsort(
    const int* __restrict__ tmp, const int* __restrict__ bbase,
    int* __restrict__ off, int* __restrict__ esrc, int N) {
    __shared__ int h[128], hs[128], cur[128];
    int b = blockIdx.x, t = threadIdx.x;
    int base = bbase[b];
    int cnt  = bbase[b + 1] - base;
    int node0 = b << 7;
    if (t < 128) h[t] = 0;
    __syncthreads();
    for (int i = t; i < cnt; i += 256) atomicAdd(&h[tmp[base + i] & 127], 1);
    __syncthreads();
    if (t < 128) hs[t] = h[t];
    __syncthreads();
    for (int ofs = 1; ofs < 128; ofs <<= 1) {
        int w = (t < 128 && t >= ofs) ? hs[t - ofs] : 0;
        __syncthreads();
        if (t < 128) hs[t] += w;
        __syncthreads();
    }
    if (t < 128) {
        int ex = hs[t] - h[t];
        if (node0 + t < N) off[node0 + t] = base + ex;
        cur[t] = base + ex;
    }
    __syncthreads();
    for (int i = t; i < cnt; i += 256) {
        int p = tmp[base + i];
        int pos = atomicAdd(&cur[p & 127], 1);
        esrc[pos] = p >> 7;
    }
}

// ---------------- MFMA GEMM + fused attention dots ----------------
// Y(fp16)[N,128] = cast16(X[N,128]) @ cast16(W[128,128]); fp32 accum.
// A-frag: m=lane&15 (row), k=(lane>>4)*8+j. B-frag: n=lane&15 (col), same k.
// C/D: col=lane&15, row=(lane>>4)*4+reg.

template <int H, typename TI>
__device__ __forceinline__ void gemm_mfma_body(
    const TI* __restrict__ X, const float* __restrict__ Wg,
    const float* __restrict__ att_s, const float* __restrict__ att_d,
    __half* __restrict__ Y, float* __restrict__ as_, float* __restrict__ ad_,
    int N, int gb, int gnb)
{
    __shared__ _Float16 Wh[128 * 128];   // [k][col]
    __shared__ _Float16 Xh[64][136];     // +8 pad: breaks 256B-stride bank clash
    const int t = threadIdx.x;
    const int lane = t & 63;
    const int wv = t >> 6;
    const int m = lane & 15;
    const int q = lane >> 4;

    // stage W fp32 -> fp16 (coalesced float4 reads)
    for (int i = t; i < 128 * 128 / 4; i += 256) {
        float4 w4 = ((const float4*)Wg)[i];
        _Float16* d = &Wh[i * 4];
        d[0] = (_Float16)w4.x; d[1] = (_Float16)w4.y;
        d[2] = (_Float16)w4.z; d[3] = (_Float16)w4.w;
    }
    __syncthreads();

    // preload all B fragments into registers (8 ntiles x 4 ksteps x 4 VGPR)
    f16x8 bfr[8][4];
#pragma unroll
    for (int nt = 0; nt < 8; nt++) {
#pragma unroll
        for (int ks = 0; ks < 4; ks++) {
            f16x8 b;
#pragma unroll
            for (int j = 0; j < 8; j++)
                b[j] = Wh[(ks * 32 + q * 8 + j) * 128 + nt * 16 + m];
            bfr[nt][ks] = b;
        }
    }
    float atts_v[8], attd_v[8];
#pragma unroll
    for (int nt = 0; nt < 8; nt++) {
        atts_v[nt] = att_s[nt * 16 + m];
        attd_v[nt] = att_d[nt * 16 + m];
    }

    for (int base = gb * 64; base < N; base += gnb * 64) {
        // stage 64 rows of X -> fp16 LDS (1024 chunks of 8 halfs, 4/thread)
        for (int i = t; i < 1024; i += 256) {
            int r = i >> 4, c8 = i & 15;
            int gr = base + r;
            _Float16* d = &Xh[r][c8 * 8];
            if (gr < N) {
                if constexpr (sizeof(TI) == 4) {
                    const float4* s = (const float4*)((const float*)X + (size_t)gr * 128 + c8 * 8);
                    float4 x0 = s[0], x1 = s[1];
                    d[0] = (_Float16)x0.x; d[1] = (_Float16)x0.y;
                    d[2] = (_Float16)x0.z; d[3] = (_Float16)x0.w;
                    d[4] = (_Float16)x1.x; d[5] = (_Float16)x1.y;
                    d[6] = (_Float16)x1.z; d[7] = (_Float16)x1.w;
                } else {
                    *(uint4*)d = *(const uint4*)((const __half*)X + (size_t)gr * 128 + c8 * 8);
                }
            } else {
                uint4 z; z.x = 0; z.y = 0; z.z = 0; z.w = 0;
                *(uint4*)d = z;
            }
        }
        __syncthreads();

        const int rowb = base + wv * 16;
        f32x4 acc[8];
#pragma unroll
        for (int nt = 0; nt < 8; nt++) { acc[nt][0] = 0.f; acc[nt][1] = 0.f; acc[nt][2] = 0.f; acc[nt][3] = 0.f; }
#pragma unroll
        for (int ks = 0; ks < 4; ks++) {
            f16x8 af = *(const f16x8*)&Xh[wv * 16 + m][ks * 32 + q * 8];
#pragma unroll
            for (int nt = 0; nt < 8; nt++)
                acc[nt] = __builtin_amdgcn_mfma_f32_16x16x32_f16(af, bfr[nt][ks], acc[nt], 0, 0, 0);
        }

        // Y writes (fp16 scalar stores; C-layout)
#pragma unroll
        for (int nt = 0; nt < 8; nt++) {
#pragma unroll
            for (int i = 0; i < 4; i++) {
                int r = rowb + q * 4 + i;
                if (r < N) Y[(size_t)r * 128 + nt * 16 + m] = __float2half(acc[nt][i]);
            }
        }

        // fused attention dots: per-lane partials, butterfly over the 16 cols
        if (H == 4) {
            float ph[4][4], pdv[4][4];
#pragma unroll
            for (int h = 0; h < 4; h++)
#pragma unroll
                for (int i = 0; i < 4; i++) {
                    ph[h][i]  = acc[2 * h][i] * atts_v[2 * h] + acc[2 * h + 1][i] * atts_v[2 * h + 1];
                    pdv[h][i] = acc[2 * h][i] * attd_v[2 * h] + acc[2 * h + 1][i] * attd_v[2 * h + 1];
                }
#pragma unroll
            for (int lvl = 0; lvl < 4; lvl++) {
                const int msk = 1 << lvl;
#pragma unroll
                for (int h = 0; h < 4; h++)
#pragma unroll
                    for (int i = 0; i < 4; i++) {
                        ph[h][i]  += __shfl_xor(ph[h][i], msk, 64);
                        pdv[h][i] += __shfl_xor(pdv[h][i], msk, 64);
                    }
            }
            if (m == 0) {
#pragma unroll
                for (int i = 0; i < 4; i++) {
                    int r = rowb + q * 4 + i;
                    if (r < N) {
#pragma unroll
                        for (int h = 0; h < 4; h++) {
                            as_[(size_t)r * 4 + h] = ph[h][i];
                            ad_[(size_t)r * 4 + h] = pdv[h][i];
                        }
                    }
                }
            }
        } else {
            float ps[4], pdv[4];
#pragma unroll
            for (int i = 0; i < 4; i++) {
                float s = 0.f, dsum = 0.f;
#pragma unroll
                for (int nt = 0; nt < 8; nt++) {
                    s    += acc[nt][i] * atts_v[nt];
                    dsum += acc[nt][i] * attd_v[nt];
                }
                ps[i] = s; pdv[i] = dsum;
            }
#pragma unroll
            for (int lvl = 0; lvl < 4; lvl++) {
                const int msk = 1 << lvl;
#pragma unroll
                for (int i = 0; i < 4; i++) {
                    ps[i]  += __shfl_xor(ps[i], msk, 64);
                    pdv[i] += __shfl_xor(pdv[i], msk, 64);
                }
            }
            if (m == 0) {
#pragma unroll
                for (int i = 0; i < 4; i++) {
                    int r = rowb + q * 4 + i;
                    if (r < N) { as_[r] = ps[i]; ad_[r] = pdv[i]; }
                }
            }
        }
        __syncthreads();   // protect Xh before next tile's staging
    }
}

template <int H, typename TI>
__global__ __launch_bounds__(256, 2) void k_gemm_mfma(
    const TI* __restrict__ X, const float* __restrict__ Wg,
    const float* __restrict__ att_s, const float* __restrict__ att_d,
    __half* __restrict__ Y, float* __restrict__ as_, float* __restrict__ ad_, int N)
{
    gemm_mfma_body<H, TI>(X, Wg, att_s, att_d, Y, as_, ad_, N, blockIdx.x, gridDim.x);
}

// Fused: GEMM1 (512 block-roles) || histogram (256 block-roles), independent
// work. Roles interleaved bid%3 so hist blocks co-schedule from dispatch 0.
__global__ __launch_bounds__(256, 2) void k_g1_hist(
    const float* __restrict__ X, const float* __restrict__ Wg,
    const float* __restrict__ att_s, const float* __restrict__ att_d,
    __half* __restrict__ Y, float* __restrict__ as_, float* __restrict__ ad_, int N,
    const int* __restrict__ dst, int* __restrict__ bcnt, int E, int NBUCK)
{
    const int bid = blockIdx.x;
    const int r = bid % 3;
    if (r < 2) {
        gemm_mfma_body<4, float>(X, Wg, att_s, att_d, Y, as_, ad_, N,
                                 (bid / 3) * 2 + r, 512);
    } else {
        hist_body(dst, bcnt, E, NBUCK, bid / 3, 256);
    }
}

// ---------------- aggregation: one wave per dst node ----------------
// R8 form (best measured): 16 lanes per edge at 16B/lane; batches of 16
// edges with all 4 uint4 loads per lane issued before consumption. Tail
// slots weight 0 (no divergence). Cross-group reduce at node end.

template <int H, typename TO>
__global__ __launch_bounds__(256) void k_agg(
    const __half* __restrict__ feat,  // [N,128] fp16
    const float* __restrict__ asrc,   // [N,H]
    const float* __restrict__ adst,   // [N,H]
    const int*   __restrict__ off,    // [N+1]
    const int*   __restrict__ esrc,   // [E]
    const float* __restrict__ bias,   // [128]
    TO*          __restrict__ out,    // [N,128]
    int N)
{
    __shared__ __attribute__((aligned(16))) int   sj[4][64];
    __shared__ __attribute__((aligned(16))) float sp[4][64 * H];  // head-major

    int wave = threadIdx.x >> 6;
    int lane = threadIdx.x & 63;
    int node = (blockIdx.x * 256 + threadIdx.x) >> 6;
    if (node >= N) return;
    int beg = off[node], end = off[node + 1];

    float adst_i[H];
#pragma unroll
    for (int h = 0; h < H; h++) adst_i[h] = adst[(size_t)node * H + h];

    const int g    = lane >> 4;                    // edge sub-slot 0..3
    const int sub  = lane & 15;                    // col octet: cols sub*8..+7
    const int head = (H == 4) ? (sub >> 2) : 0;    // 32 cols per head
    const __half* fb = feat + sub * 8;

    float o[8];
#pragma unroll
    for (int k = 0; k < 8; k++) o[k] = 0.f;
    float ssum = 0.f;

    for (int cbeg = beg; cbeg < end; cbeg += 64) {
        int cnt = end - cbeg; if (cnt > 64) cnt = 64;
        if (lane < cnt) {
            int j = esrc[cbeg + lane];
            sj[wave][lane] = j;
            if (H == 4) {
                float4 av = *(const float4*)(asrc + (size_t)j * 4);
                float e;
                e = av.x + adst_i[0]; e = e > 0.f ? e : 0.2f * e; sp[wave][0 * 64 + lane] = __expf(e);
                e = av.y + adst_i[1]; e = e > 0.f ? e : 0.2f * e; sp[wave][1 * 64 + lane] = __expf(e);
                e = av.z + adst_i[2]; e = e > 0.f ? e : 0.2f * e; sp[wave][2 * 64 + lane] = __expf(e);
                e = av.w + adst_i[3]; e = e > 0.f ? e : 0.2f * e; sp[wave][3 * 64 + lane] = __expf(e);
            } else {
                float e = asrc[j] + adst_i[0];
                e = e > 0.f ? e : 0.2f * e;
                sp[wave][lane] = __expf(e);
            }
        }
        asm volatile("s_waitcnt lgkmcnt(0)" ::: "memory");

        // batches of 16 edges: issue 4 gathers back-to-back, then consume.
        for (int b0 = 0; b0 < cnt; b0 += 16) {
            float aa[4]; uint4 hv[4];
#pragma unroll
            for (int u = 0; u < 4; u++) {
                int e  = b0 + 4 * u + g;
                bool ok = e < cnt;
                int ec = ok ? e : 0;
                int j  = sj[wave][ec];
                aa[u]  = ok ? sp[wave][head * 64 + ec] : 0.f;
                hv[u]  = *(const uint4*)(fb + (size_t)j * 128);
            }
#pragma unroll
            for (int u = 0; u < 4; u++) {
                const __half* hp = (const __half*)&hv[u];
                ssum += aa[u];
#pragma unroll
                for (int k = 0; k < 8; k++)
                    o[k] = fmaf(aa[u], __half2float(hp[k]), o[k]);
            }
        }
        // same-wave lockstep: staging of the next chunk cannot race these reads
    }

    // reduce across the 4 edge-groups (lanes with equal sub share cols/head)
#pragma unroll
    for (int k = 0; k < 8; k++) {
        o[k] += __shfl_xor(o[k], 16, 64);
        o[k] += __shfl_xor(o[k], 32, 64);
    }
    ssum += __shfl_xor(ssum, 16, 64);
    ssum += __shfl_xor(ssum, 32, 64);

    if (g == 0) {
        float inv = 1.f / (ssum + 1e-16f);
        float r[8];
#pragma unroll
        for (int k = 0; k < 8; k++) {
            r[k] = o[k] * inv + bias[sub * 8 + k];
            r[k] = r[k] > 0.f ? r[k] : expm1f(r[k]);
        }
        if constexpr (sizeof(TO) == 2) {
            __half2 hh[4];
#pragma unroll
            for (int p = 0; p < 4; p++) hh[p] = __floats2half2_rn(r[2 * p], r[2 * p + 1]);
            *(uint4*)((__half*)out + (size_t)node * 128 + sub * 8) = *(const uint4*)hh;
        } else {
            float4 v0 = make_float4(r[0], r[1], r[2], r[3]);
            float4 v1 = make_float4(r[4], r[5], r[6], r[7]);
            *(float4*)((float*)out + (size_t)node * 128 + sub * 8)     = v0;
            *(float4*)((float*)out + (size_t)node * 128 + sub * 8 + 4) = v1;
        }
    }
}

// ---------------- launch ----------------

extern "C" void kernel_launch(void* const* d_in, const int* in_sizes, int n_in,
                              void* d_out, int out_size, void* d_ws, size_t ws_size,
                              hipStream_t stream)
{
    const float* x    = (const float*)d_in[0];
    const int*   a    = (const int*)  d_in[1];
    const float* W1   = (const float*)d_in[2];
    const float* as1w = (const float*)d_in[3];
    const float* ad1w = (const float*)d_in[4];
    const float* b1   = (const float*)d_in[5];
    const float* W2   = (const float*)d_in[6];
    const float* as2w = (const float*)d_in[7];
    const float* ad2w = (const float*)d_in[8];
    const float* b2   = (const float*)d_in[9];

    const int N = in_sizes[0] / 128;
    const int E = in_sizes[1] / 2;
    const int* srcA = a;
    const int* dstA = a + E;
    const int NBUCK = (N + 127) >> 7;

    char* ws = (char*)d_ws;
    size_t o = 0;
    auto alloc = [&](size_t bytes) -> void* {
        void* p = ws + o;
        o += (bytes + 255) & ~(size_t)255;
        return p;
    };
    __half* hbuf  = (__half*)alloc((size_t)N * 128 * 2);  // fp16 gather payload
    __half* hact  = (__half*)alloc((size_t)N * 128 * 2);  // elu(gat1) fp16, GEMM2 input
    float*  as1   = (float*) alloc((size_t)N * 4 * 4);
    float*  ad1   = (float*) alloc((size_t)N * 4 * 4);
    float*  as2   = (float*) alloc((size_t)N * 4);
    float*  ad2   = (float*) alloc((size_t)N * 4);
    int*    off   = (int*)   alloc((size_t)(N + 1) * 4);
    int*    esrc  = (int*)   alloc((size_t)E * 4);
    int*    tmp   = (int*)   alloc((size_t)E * 4);
    int*    bcnt  = (int*)   alloc(1024 * 4);
    int*    bbase = (int*)   alloc(1025 * 4);
    int*    bcur  = (int*)   alloc(1024 * 4);

    // CSR build (rebuilt each launch; ws is re-poisoned)
    hipMemsetAsync(bcnt, 0, (size_t)NBUCK * 4, stream);

    // fused: GEMM1 + histogram (independent of each other)
    k_g1_hist<<<768, 256, 0, stream>>>(x, W1, as1w, ad1w, hbuf, as1, ad1, N,
                                       dstA, bcnt, E, NBUCK);

    k_bscan<<<1, 1024, 0, stream>>>(bcnt, bbase, bcur, off, NBUCK, N, E);
    k_binscatter<<<(E + 8191) / 8192, 256, 0, stream>>>(srcA, dstA, bcur, tmp, E, NBUCK);
    k_bsort<<<NBUCK, 256, 0, stream>>>(tmp, bbase, off, esrc, N);

    // layer 1 aggregation
    k_agg<4, __half><<<(N + 3) / 4, 256, 0, stream>>>(hbuf, as1, ad1, off, esrc, b1, hact, N);

    // layer 2
    k_gemm_mfma<1, __half><<<512, 256, 0, stream>>>(hact, W2, as2w, ad2w, hbuf, as2, ad2, N);
    k_agg<1, float><<<(N + 3) / 4, 256, 0, stream>>>(hbuf, as2, ad2, off, esrc, b2, (float*)d_out, N);
}

// Round 7
// 358.167 us; speedup vs baseline: 1.4140x; 1.1465x over previous
//
#include <hip/hip_runtime.h>
#include <hip/hip_fp16.h>
#include <math.h>

// ---------------------------------------------------------------------------
// GAT graph encoder: 2x GATConv (PyG semantics, add_self_loops=False)
// R10->R11: hist-fusion reverted (measured neutral, +5us ~ noise). k_agg is
//   VALU-ISSUE-bound (~900 VALU instr/node at VALUBusy 80%), not fabric-BW
//   bound: expm1f is a libm accurate-path call (~25-40 ops) x 8 outputs
//   (~300 instr/node, full-wave issue under the g==0 mask). Replace with
//   __expf(r)-1.0f (absolute error ~1e-6, ELU-safe). Everything else is the
//   measured-best R8 structure, unchanged.
// ---------------------------------------------------------------------------

typedef _Float16 f16x8 __attribute__((ext_vector_type(8)));
typedef float    f32x4 __attribute__((ext_vector_type(4)));

// ---------------- CSR build ----------------

__global__ __launch_bounds__(256) void k_hist(const int* __restrict__ dst,
                                              int* __restrict__ bcnt, int E, int NBUCK) {
    __shared__ int lh[1024];
    int t = threadIdx.x;
    for (int i = t; i < NBUCK; i += 256) lh[i] = 0;
    __syncthreads();
    for (int e = blockIdx.x * 256 + t; e < E; e += gridDim.x * 256)
        atomicAdd(&lh[dst[e] >> 7], 1);
    __syncthreads();
    for (int i = t; i < NBUCK; i += 256) {
        int c = lh[i];
        if (c) atomicAdd(&bcnt[i], c);
    }
}

__global__ void k_bscan(const int* __restrict__ bcnt, int* __restrict__ bbase,
                        int* __restrict__ bcur, int* __restrict__ off,
                        int NBUCK, int N, int E) {
    __shared__ int sd[1024];
    int t = threadIdx.x;
    int v = (t < NBUCK) ? bcnt[t] : 0;
    sd[t] = v; __syncthreads();
    for (int ofs = 1; ofs < 1024; ofs <<= 1) {
        int w = (t >= ofs) ? sd[t - ofs] : 0;
        __syncthreads();
        sd[t] += w;
        __syncthreads();
    }
    if (t < NBUCK) { int ex = sd[t] - v; bbase[t] = ex; bcur[t] = ex; }
    if (t == 0) { bbase[NBUCK] = E; off[N] = E; }
}

__global__ __launch_bounds__(256) void k_binscatter(
    const int* __restrict__ src, const int* __restrict__ dst,
    int* __restrict__ bcur, int* __restrict__ tmp, int E, int NBUCK) {
    __shared__ int lh[1024], lbase[1024];
    int t = threadIdx.x;
    for (int i = t; i < NBUCK; i += 256) lh[i] = 0;
    __syncthreads();
    int tbeg = blockIdx.x * 8192;
    int tend = tbeg + 8192; if (tend > E) tend = E;
    for (int e = tbeg + t; e < tend; e += 256) atomicAdd(&lh[dst[e] >> 7], 1);
    __syncthreads();
    for (int i = t; i < NBUCK; i += 256) {
        int c = lh[i];
        lbase[i] = c ? atomicAdd(&bcur[i], c) : 0;
        lh[i] = 0;
    }
    __syncthreads();
    for (int e = tbeg + t; e < tend; e += 256) {
        int d = dst[e];
        int b = d >> 7;
        int r = atomicAdd(&lh[b], 1);
        tmp[lbase[b] + r] = (src[e] << 7) | (d & 127);
    }
}

__global__ __launch_bounds__(256) void k_bsort(
    const int* __restrict__ tmp, const int* __restrict__ bbase,
    int* __restrict__ off, int* __restrict__ esrc, int N) {
    __shared__ int h[128], hs[128], cur[128];
    int b = blockIdx.x, t = threadIdx.x;
    int base = bbase[b];
    int cnt  = bbase[b + 1] - base;
    int node0 = b << 7;
    if (t < 128) h[t] = 0;
    __syncthreads();
    for (int i = t; i < cnt; i += 256) atomicAdd(&h[tmp[base + i] & 127], 1);
    __syncthreads();
    if (t < 128) hs[t] = h[t];
    __syncthreads();
    for (int ofs = 1; ofs < 128; ofs <<= 1) {
        int w = (t < 128 && t >= ofs) ? hs[t - ofs] : 0;
        __syncthreads();
        if (t < 128) hs[t] += w;
        __syncthreads();
    }
    if (t < 128) {
        int ex = hs[t] - h[t];
        if (node0 + t < N) off[node0 + t] = base + ex;
        cur[t] = base + ex;
    }
    __syncthreads();
    for (int i = t; i < cnt; i += 256) {
        int p = tmp[base + i];
        int pos = atomicAdd(&cur[p & 127], 1);
        esrc[pos] = p >> 7;
    }
}

// ---------------- MFMA GEMM + fused attention dots ----------------
// Y(fp16)[N,128] = cast16(X[N,128]) @ cast16(W[128,128]); fp32 accum.
// A-frag: m=lane&15 (row), k=(lane>>4)*8+j. B-frag: n=lane&15 (col), same k.
// C/D: col=lane&15, row=(lane>>4)*4+reg.

template <int H, typename TI>
__global__ __launch_bounds__(256, 2) void k_gemm_mfma(
    const TI* __restrict__ X, const float* __restrict__ Wg,
    const float* __restrict__ att_s, const float* __restrict__ att_d,
    __half* __restrict__ Y, float* __restrict__ as_, float* __restrict__ ad_, int N)
{
    __shared__ _Float16 Wh[128 * 128];   // [k][col]
    __shared__ _Float16 Xh[64][136];     // +8 pad: breaks 256B-stride bank clash
    const int t = threadIdx.x;
    const int lane = t & 63;
    const int wv = t >> 6;
    const int m = lane & 15;
    const int q = lane >> 4;

    // stage W fp32 -> fp16 (coalesced float4 reads)
    for (int i = t; i < 128 * 128 / 4; i += 256) {
        float4 w4 = ((const float4*)Wg)[i];
        _Float16* d = &Wh[i * 4];
        d[0] = (_Float16)w4.x; d[1] = (_Float16)w4.y;
        d[2] = (_Float16)w4.z; d[3] = (_Float16)w4.w;
    }
    __syncthreads();

    // preload all B fragments into registers (8 ntiles x 4 ksteps x 4 VGPR)
    f16x8 bfr[8][4];
#pragma unroll
    for (int nt = 0; nt < 8; nt++) {
#pragma unroll
        for (int ks = 0; ks < 4; ks++) {
            f16x8 b;
#pragma unroll
            for (int j = 0; j < 8; j++)
                b[j] = Wh[(ks * 32 + q * 8 + j) * 128 + nt * 16 + m];
            bfr[nt][ks] = b;
        }
    }
    float atts_v[8], attd_v[8];
#pragma unroll
    for (int nt = 0; nt < 8; nt++) {
        atts_v[nt] = att_s[nt * 16 + m];
        attd_v[nt] = att_d[nt * 16 + m];
    }

    for (int base = blockIdx.x * 64; base < N; base += gridDim.x * 64) {
        // stage 64 rows of X -> fp16 LDS (1024 chunks of 8 halfs, 4/thread)
        for (int i = t; i < 1024; i += 256) {
            int r = i >> 4, c8 = i & 15;
            int gr = base + r;
            _Float16* d = &Xh[r][c8 * 8];
            if (gr < N) {
                if constexpr (sizeof(TI) == 4) {
                    const float4* s = (const float4*)((const float*)X + (size_t)gr * 128 + c8 * 8);
                    float4 x0 = s[0], x1 = s[1];
                    d[0] = (_Float16)x0.x; d[1] = (_Float16)x0.y;
                    d[2] = (_Float16)x0.z; d[3] = (_Float16)x0.w;
                    d[4] = (_Float16)x1.x; d[5] = (_Float16)x1.y;
                    d[6] = (_Float16)x1.z; d[7] = (_Float16)x1.w;
                } else {
                    *(uint4*)d = *(const uint4*)((const __half*)X + (size_t)gr * 128 + c8 * 8);
                }
            } else {
                uint4 z; z.x = 0; z.y = 0; z.z = 0; z.w = 0;
                *(uint4*)d = z;
            }
        }
        __syncthreads();

        const int rowb = base + wv * 16;
        f32x4 acc[8];
#pragma unroll
        for (int nt = 0; nt < 8; nt++) { acc[nt][0] = 0.f; acc[nt][1] = 0.f; acc[nt][2] = 0.f; acc[nt][3] = 0.f; }
#pragma unroll
        for (int ks = 0; ks < 4; ks++) {
            f16x8 af = *(const f16x8*)&Xh[wv * 16 + m][ks * 32 + q * 8];
#pragma unroll
            for (int nt = 0; nt < 8; nt++)
                acc[nt] = __builtin_amdgcn_mfma_f32_16x16x32_f16(af, bfr[nt][ks], acc[nt], 0, 0, 0);
        }

        // Y writes (fp16 scalar stores; C-layout)
#pragma unroll
        for (int nt = 0; nt < 8; nt++) {
#pragma unroll
            for (int i = 0; i < 4; i++) {
                int r = rowb + q * 4 + i;
                if (r < N) Y[(size_t)r * 128 + nt * 16 + m] = __float2half(acc[nt][i]);
            }
        }

        // fused attention dots: per-lane partials, butterfly over the 16 cols
        if (H == 4) {
            float ph[4][4], pdv[4][4];
#pragma unroll
            for (int h = 0; h < 4; h++)
#pragma unroll
                for (int i = 0; i < 4; i++) {
                    ph[h][i]  = acc[2 * h][i] * atts_v[2 * h] + acc[2 * h + 1][i] * atts_v[2 * h + 1];
                    pdv[h][i] = acc[2 * h][i] * attd_v[2 * h] + acc[2 * h + 1][i] * attd_v[2 * h + 1];
                }
#pragma unroll
            for (int lvl = 0; lvl < 4; lvl++) {
                const int msk = 1 << lvl;
#pragma unroll
                for (int h = 0; h < 4; h++)
#pragma unroll
                    for (int i = 0; i < 4; i++) {
                        ph[h][i]  += __shfl_xor(ph[h][i], msk, 64);
                        pdv[h][i] += __shfl_xor(pdv[h][i], msk, 64);
                    }
            }
            if (m == 0) {
#pragma unroll
                for (int i = 0; i < 4; i++) {
                    int r = rowb + q * 4 + i;
                    if (r < N) {
#pragma unroll
                        for (int h = 0; h < 4; h++) {
                            as_[(size_t)r * 4 + h] = ph[h][i];
                            ad_[(size_t)r * 4 + h] = pdv[h][i];
                        }
                    }
                }
            }
        } else {
            float ps[4], pdv[4];
#pragma unroll
            for (int i = 0; i < 4; i++) {
                float s = 0.f, dsum = 0.f;
#pragma unroll
                for (int nt = 0; nt < 8; nt++) {
                    s    += acc[nt][i] * atts_v[nt];
                    dsum += acc[nt][i] * attd_v[nt];
                }
                ps[i] = s; pdv[i] = dsum;
            }
#pragma unroll
            for (int lvl = 0; lvl < 4; lvl++) {
                const int msk = 1 << lvl;
#pragma unroll
                for (int i = 0; i < 4; i++) {
                    ps[i]  += __shfl_xor(ps[i], msk, 64);
                    pdv[i] += __shfl_xor(pdv[i], msk, 64);
                }
            }
            if (m == 0) {
#pragma unroll
                for (int i = 0; i < 4; i++) {
                    int r = rowb + q * 4 + i;
                    if (r < N) { as_[r] = ps[i]; ad_[r] = pdv[i]; }
                }
            }
        }
        __syncthreads();   // protect Xh before next tile's staging
    }
}

// ---------------- aggregation: one wave per dst node ----------------
// R8 form + cheap ELU (R11): 16 lanes per edge at 16B/lane; batches of 16
// edges with all 4 uint4 loads per lane issued before consumption. Tail
// slots weight 0 (no divergence). Cross-group reduce at node end.
// ELU epilogue: __expf(r)-1 (3-4 VALU) instead of libm expm1f (~25-40 VALU
// x 8 outputs -> ~300 instr/node saved; absolute error ~1e-6, ELU-safe).

template <int H, typename TO>
__global__ __launch_bounds__(256) void k_agg(
    const __half* __restrict__ feat,  // [N,128] fp16
    const float* __restrict__ asrc,   // [N,H]
    const float* __restrict__ adst,   // [N,H]
    const int*   __restrict__ off,    // [N+1]
    const int*   __restrict__ esrc,   // [E]
    const float* __restrict__ bias,   // [128]
    TO*          __restrict__ out,    // [N,128]
    int N)
{
    __shared__ __attribute__((aligned(16))) int   sj[4][64];
    __shared__ __attribute__((aligned(16))) float sp[4][64 * H];  // head-major

    int wave = threadIdx.x >> 6;
    int lane = threadIdx.x & 63;
    int node = (blockIdx.x * 256 + threadIdx.x) >> 6;
    if (node >= N) return;
    int beg = off[node], end = off[node + 1];

    float adst_i[H];
#pragma unroll
    for (int h = 0; h < H; h++) adst_i[h] = adst[(size_t)node * H + h];

    const int g    = lane >> 4;                    // edge sub-slot 0..3
    const int sub  = lane & 15;                    // col octet: cols sub*8..+7
    const int head = (H == 4) ? (sub >> 2) : 0;    // 32 cols per head
    const __half* fb = feat + sub * 8;

    float o[8];
#pragma unroll
    for (int k = 0; k < 8; k++) o[k] = 0.f;
    float ssum = 0.f;

    for (int cbeg = beg; cbeg < end; cbeg += 64) {
        int cnt = end - cbeg; if (cnt > 64) cnt = 64;
        if (lane < cnt) {
            int j = esrc[cbeg + lane];
            sj[wave][lane] = j;
            if (H == 4) {
                float4 av = *(const float4*)(asrc + (size_t)j * 4);
                float e;
                e = av.x + adst_i[0]; e = e > 0.f ? e : 0.2f * e; sp[wave][0 * 64 + lane] = __expf(e);
                e = av.y + adst_i[1]; e = e > 0.f ? e : 0.2f * e; sp[wave][1 * 64 + lane] = __expf(e);
                e = av.z + adst_i[2]; e = e > 0.f ? e : 0.2f * e; sp[wave][2 * 64 + lane] = __expf(e);
                e = av.w + adst_i[3]; e = e > 0.f ? e : 0.2f * e; sp[wave][3 * 64 + lane] = __expf(e);
            } else {
                float e = asrc[j] + adst_i[0];
                e = e > 0.f ? e : 0.2f * e;
                sp[wave][lane] = __expf(e);
            }
        }
        asm volatile("s_waitcnt lgkmcnt(0)" ::: "memory");

        // batches of 16 edges: issue 4 gathers back-to-back, then consume.
        for (int b0 = 0; b0 < cnt; b0 += 16) {
            float aa[4]; uint4 hv[4];
#pragma unroll
            for (int u = 0; u < 4; u++) {
                int e  = b0 + 4 * u + g;
                bool ok = e < cnt;
                int ec = ok ? e : 0;
                int j  = sj[wave][ec];
                aa[u]  = ok ? sp[wave][head * 64 + ec] : 0.f;
                hv[u]  = *(const uint4*)(fb + (size_t)j * 128);
            }
#pragma unroll
            for (int u = 0; u < 4; u++) {
                const __half* hp = (const __half*)&hv[u];
                ssum += aa[u];
#pragma unroll
                for (int k = 0; k < 8; k++)
                    o[k] = fmaf(aa[u], __half2float(hp[k]), o[k]);
            }
        }
        // same-wave lockstep: staging of the next chunk cannot race these reads
    }

    // reduce across the 4 edge-groups (lanes with equal sub share cols/head)
#pragma unroll
    for (int k = 0; k < 8; k++) {
        o[k] += __shfl_xor(o[k], 16, 64);
        o[k] += __shfl_xor(o[k], 32, 64);
    }
    ssum += __shfl_xor(ssum, 16, 64);
    ssum += __shfl_xor(ssum, 32, 64);

    if (g == 0) {
        float inv = 1.f / (ssum + 1e-16f);
        float r[8];
#pragma unroll
        for (int k = 0; k < 8; k++) {
            r[k] = o[k] * inv + bias[sub * 8 + k];
            float er = __expf(r[k]) - 1.0f;          // cheap ELU branch (abs err ~1e-6)
            r[k] = r[k] > 0.f ? r[k] : er;
        }
        if constexpr (sizeof(TO) == 2) {
            __half2 hh[4];
#pragma unroll
            for (int p = 0; p < 4; p++) hh[p] = __floats2half2_rn(r[2 * p], r[2 * p + 1]);
            *(uint4*)((__half*)out + (size_t)node * 128 + sub * 8) = *(const uint4*)hh;
        } else {
            float4 v0 = make_float4(r[0], r[1], r[2], r[3]);
            float4 v1 = make_float4(r[4], r[5], r[6], r[7]);
            *(float4*)((float*)out + (size_t)node * 128 + sub * 8)     = v0;
            *(float4*)((float*)out + (size_t)node * 128 + sub * 8 + 4) = v1;
        }
    }
}

// ---------------- launch ----------------

extern "C" void kernel_launch(void* const* d_in, const int* in_sizes, int n_in,
                              void* d_out, int out_size, void* d_ws, size_t ws_size,
                              hipStream_t stream)
{
    const float* x    = (const float*)d_in[0];
    const int*   a    = (const int*)  d_in[1];
    const float* W1   = (const float*)d_in[2];
    const float* as1w = (const float*)d_in[3];
    const float* ad1w = (const float*)d_in[4];
    const float* b1   = (const float*)d_in[5];
    const float* W2   = (const float*)d_in[6];
    const float* as2w = (const float*)d_in[7];
    const float* ad2w = (const float*)d_in[8];
    const float* b2   = (const float*)d_in[9];

    const int N = in_sizes[0] / 128;
    const int E = in_sizes[1] / 2;
    const int* srcA = a;
    const int* dstA = a + E;
    const int NBUCK = (N + 127) >> 7;

    char* ws = (char*)d_ws;
    size_t o = 0;
    auto alloc = [&](size_t bytes) -> void* {
        void* p = ws + o;
        o += (bytes + 255) & ~(size_t)255;
        return p;
    };
    __half* hbuf  = (__half*)alloc((size_t)N * 128 * 2);  // fp16 gather payload
    __half* hact  = (__half*)alloc((size_t)N * 128 * 2);  // elu(gat1) fp16, GEMM2 input
    float*  as1   = (float*) alloc((size_t)N * 4 * 4);
    float*  ad1   = (float*) alloc((size_t)N * 4 * 4);
    float*  as2   = (float*) alloc((size_t)N * 4);
    float*  ad2   = (float*) alloc((size_t)N * 4);
    int*    off   = (int*)   alloc((size_t)(N + 1) * 4);
    int*    esrc  = (int*)   alloc((size_t)E * 4);
    int*    tmp   = (int*)   alloc((size_t)E * 4);
    int*    bcnt  = (int*)   alloc(1024 * 4);
    int*    bbase = (int*)   alloc(1025 * 4);
    int*    bcur  = (int*)   alloc(1024 * 4);

    // CSR build (rebuilt each launch; ws is re-poisoned)
    hipMemsetAsync(bcnt, 0, (size_t)NBUCK * 4, stream);
    k_hist<<<256, 256, 0, stream>>>(dstA, bcnt, E, NBUCK);
    k_bscan<<<1, 1024, 0, stream>>>(bcnt, bbase, bcur, off, NBUCK, N, E);
    k_binscatter<<<(E + 8191) / 8192, 256, 0, stream>>>(srcA, dstA, bcur, tmp, E, NBUCK);
    k_bsort<<<NBUCK, 256, 0, stream>>>(tmp, bbase, off, esrc, N);

    // layer 1 (MFMA GEMM + fused attdot, fp16 Y)
    k_gemm_mfma<4, float><<<512, 256, 0, stream>>>(x, W1, as1w, ad1w, hbuf, as1, ad1, N);
    k_agg<4, __half><<<(N + 3) / 4, 256, 0, stream>>>(hbuf, as1, ad1, off, esrc, b1, hact, N);

    // layer 2
    k_gemm_mfma<1, __half><<<512, 256, 0, stream>>>(hact, W2, as2w, ad2w, hbuf, as2, ad2, N);
    k_agg<1, float><<<(N + 3) / 4, 256, 0, stream>>>(hbuf, as2, ad2, off, esrc, b2, (float*)d_out, N);
}

// Round 8
// 347.812 us; speedup vs baseline: 1.4561x; 1.0298x over previous
//
#include <hip/hip_runtime.h>
#include <hip/hip_fp16.h>
#include <math.h>

// ---------------------------------------------------------------------------
// GAT graph encoder: 2x GATConv (PyG semantics, add_self_loops=False)
// R11->R12:
//  (a) k_agg: groups own 4 CONSECUTIVE edges -> per-batch int4/float4 LDS
//      reads (2 vector ops vs 8 scalar) + full/tail batch split (steady
//      state unpredicated). Edge order within node changes (already
//      nondeterministic via atomic bucket sort; summation tolerance-tested).
//  (b) k_gemm_mfma: W staged into LDS FRAGMENT-MAJOR (lane's 8-half B-frag
//      contiguous -> ds_read_b128), fragments streamed in the nt loop
//      instead of a 128-VGPR preload; __launch_bounds__(256,3) -> 3 blocks
//      /CU (12 waves/CU vs 8). Grid 768. Theory: GEMM was occupancy/latency
//      bound at 2 waves/SIMD.
// R11 cheap-ELU epilogue kept (WIN: k_agg 91.5->71.1us, total 405->358).
// ---------------------------------------------------------------------------

typedef _Float16 f16x8 __attribute__((ext_vector_type(8)));
typedef float    f32x4 __attribute__((ext_vector_type(4)));

// ---------------- CSR build ----------------

__global__ __launch_bounds__(256) void k_hist(const int* __restrict__ dst,
                                              int* __restrict__ bcnt, int E, int NBUCK) {
    __shared__ int lh[1024];
    int t = threadIdx.x;
    for (int i = t; i < NBUCK; i += 256) lh[i] = 0;
    __syncthreads();
    for (int e = blockIdx.x * 256 + t; e < E; e += gridDim.x * 256)
        atomicAdd(&lh[dst[e] >> 7], 1);
    __syncthreads();
    for (int i = t; i < NBUCK; i += 256) {
        int c = lh[i];
        if (c) atomicAdd(&bcnt[i], c);
    }
}

__global__ void k_bscan(const int* __restrict__ bcnt, int* __restrict__ bbase,
                        int* __restrict__ bcur, int* __restrict__ off,
                        int NBUCK, int N, int E) {
    __shared__ int sd[1024];
    int t = threadIdx.x;
    int v = (t < NBUCK) ? bcnt[t] : 0;
    sd[t] = v; __syncthreads();
    for (int ofs = 1; ofs < 1024; ofs <<= 1) {
        int w = (t >= ofs) ? sd[t - ofs] : 0;
        __syncthreads();
        sd[t] += w;
        __syncthreads();
    }
    if (t < NBUCK) { int ex = sd[t] - v; bbase[t] = ex; bcur[t] = ex; }
    if (t == 0) { bbase[NBUCK] = E; off[N] = E; }
}

__global__ __launch_bounds__(256) void k_binscatter(
    const int* __restrict__ src, const int* __restrict__ dst,
    int* __restrict__ bcur, int* __restrict__ tmp, int E, int NBUCK) {
    __shared__ int lh[1024], lbase[1024];
    int t = threadIdx.x;
    for (int i = t; i < NBUCK; i += 256) lh[i] = 0;
    __syncthreads();
    int tbeg = blockIdx.x * 8192;
    int tend = tbeg + 8192; if (tend > E) tend = E;
    for (int e = tbeg + t; e < tend; e += 256) atomicAdd(&lh[dst[e] >> 7], 1);
    __syncthreads();
    for (int i = t; i < NBUCK; i += 256) {
        int c = lh[i];
        lbase[i] = c ? atomicAdd(&bcur[i], c) : 0;
        lh[i] = 0;
    }
    __syncthreads();
    for (int e = tbeg + t; e < tend; e += 256) {
        int d = dst[e];
        int b = d >> 7;
        int r = atomicAdd(&lh[b], 1);
        tmp[lbase[b] + r] = (src[e] << 7) | (d & 127);
    }
}

__global__ __launch_bounds__(256) void k_bsort(
    const int* __restrict__ tmp, const int* __restrict__ bbase,
    int* __restrict__ off, int* __restrict__ esrc, int N) {
    __shared__ int h[128], hs[128], cur[128];
    int b = blockIdx.x, t = threadIdx.x;
    int base = bbase[b];
    int cnt  = bbase[b + 1] - base;
    int node0 = b << 7;
    if (t < 128) h[t] = 0;
    __syncthreads();
    for (int i = t; i < cnt; i += 256) atomicAdd(&h[tmp[base + i] & 127], 1);
    __syncthreads();
    if (t < 128) hs[t] = h[t];
    __syncthreads();
    for (int ofs = 1; ofs < 128; ofs <<= 1) {
        int w = (t < 128 && t >= ofs) ? hs[t - ofs] : 0;
        __syncthreads();
        if (t < 128) hs[t] += w;
        __syncthreads();
    }
    if (t < 128) {
        int ex = hs[t] - h[t];
        if (node0 + t < N) off[node0 + t] = base + ex;
        cur[t] = base + ex;
    }
    __syncthreads();
    for (int i = t; i < cnt; i += 256) {
        int p = tmp[base + i];
        int pos = atomicAdd(&cur[p & 127], 1);
        esrc[pos] = p >> 7;
    }
}

// ---------------- MFMA GEMM + fused attention dots ----------------
// Y(fp16)[N,128] = cast16(X[N,128]) @ cast16(W[128,128]); fp32 accum.
// A-frag: m=lane&15 (row), k=(lane>>4)*8+j. B-frag: n=lane&15 (col), same k.
// C/D: col=lane&15, row=(lane>>4)*4+reg.
// R12: W in LDS fragment-major: Wf[nt][ks][lane*8 + j] holds
//   W[ks*32 + (lane>>4)*8 + j][nt*16 + (lane&15)]  -> per-(nt,ks) fragment
//   is ONE aligned ds_read_b128 per lane. Fragments streamed per nt (no
//   128-VGPR resident preload) -> 3 blocks/CU.

template <int H, typename TI>
__global__ __launch_bounds__(256, 3) void k_gemm_mfma(
    const TI* __restrict__ X, const float* __restrict__ Wg,
    const float* __restrict__ att_s, const float* __restrict__ att_d,
    __half* __restrict__ Y, float* __restrict__ as_, float* __restrict__ ad_, int N)
{
    __shared__ _Float16 Wf[8][4][512];   // [nt][ks][lane*8+j], 32 KB
    __shared__ _Float16 Xh[64][136];     // +8 pad: breaks 256B-stride bank clash
    const int t = threadIdx.x;
    const int lane = t & 63;
    const int wv = t >> 6;
    const int m = lane & 15;
    const int q = lane >> 4;

    // stage W fp32 -> fp16 fragment-major: 2048 fragments, 8 per thread.
    // Each fragment = 8 W elements down one column (j = k&7 contiguity).
    for (int f = t; f < 2048; f += 256) {
        int nt = f >> 8, ks = (f >> 6) & 3, ls = f & 63;
        int qq = ls >> 4, mm = ls & 15;
        int col = nt * 16 + mm;
        int k0  = ks * 32 + qq * 8;
        f16x8 frag;
#pragma unroll
        for (int j = 0; j < 8; j++)
            frag[j] = (_Float16)Wg[(size_t)(k0 + j) * 128 + col];
        *(f16x8*)&Wf[nt][ks][ls * 8] = frag;
    }

    float atts_v[8], attd_v[8];
#pragma unroll
    for (int nt = 0; nt < 8; nt++) {
        atts_v[nt] = att_s[nt * 16 + m];
        attd_v[nt] = att_d[nt * 16 + m];
    }
    __syncthreads();

    for (int base = blockIdx.x * 64; base < N; base += gridDim.x * 64) {
        // stage 64 rows of X -> fp16 LDS (1024 chunks of 8 halfs, 4/thread)
        for (int i = t; i < 1024; i += 256) {
            int r = i >> 4, c8 = i & 15;
            int gr = base + r;
            _Float16* d = &Xh[r][c8 * 8];
            if (gr < N) {
                if constexpr (sizeof(TI) == 4) {
                    const float4* s = (const float4*)((const float*)X + (size_t)gr * 128 + c8 * 8);
                    float4 x0 = s[0], x1 = s[1];
                    d[0] = (_Float16)x0.x; d[1] = (_Float16)x0.y;
                    d[2] = (_Float16)x0.z; d[3] = (_Float16)x0.w;
                    d[4] = (_Float16)x1.x; d[5] = (_Float16)x1.y;
                    d[6] = (_Float16)x1.z; d[7] = (_Float16)x1.w;
                } else {
                    *(uint4*)d = *(const uint4*)((const __half*)X + (size_t)gr * 128 + c8 * 8);
                }
            } else {
                uint4 z; z.x = 0; z.y = 0; z.z = 0; z.w = 0;
                *(uint4*)d = z;
            }
        }
        __syncthreads();

        const int rowb = base + wv * 16;

        // A-fragments for this wave's 16 rows (4 x ds_read_b128)
        f16x8 af[4];
#pragma unroll
        for (int ks = 0; ks < 4; ks++)
            af[ks] = *(const f16x8*)&Xh[wv * 16 + m][ks * 32 + q * 8];

        f32x4 acc[8];
#pragma unroll
        for (int nt = 0; nt < 8; nt++) { acc[nt][0] = 0.f; acc[nt][1] = 0.f; acc[nt][2] = 0.f; acc[nt][3] = 0.f; }

        // stream B-fragments from LDS per nt (4 x ds_read_b128 + 4 MFMA)
#pragma unroll
        for (int nt = 0; nt < 8; nt++) {
            f16x8 b0v = *(const f16x8*)&Wf[nt][0][lane * 8];
            f16x8 b1v = *(const f16x8*)&Wf[nt][1][lane * 8];
            f16x8 b2v = *(const f16x8*)&Wf[nt][2][lane * 8];
            f16x8 b3v = *(const f16x8*)&Wf[nt][3][lane * 8];
            acc[nt] = __builtin_amdgcn_mfma_f32_16x16x32_f16(af[0], b0v, acc[nt], 0, 0, 0);
            acc[nt] = __builtin_amdgcn_mfma_f32_16x16x32_f16(af[1], b1v, acc[nt], 0, 0, 0);
            acc[nt] = __builtin_amdgcn_mfma_f32_16x16x32_f16(af[2], b2v, acc[nt], 0, 0, 0);
            acc[nt] = __builtin_amdgcn_mfma_f32_16x16x32_f16(af[3], b3v, acc[nt], 0, 0, 0);
        }

        // Y writes (fp16 scalar stores; C-layout)
#pragma unroll
        for (int nt = 0; nt < 8; nt++) {
#pragma unroll
            for (int i = 0; i < 4; i++) {
                int r = rowb + q * 4 + i;
                if (r < N) Y[(size_t)r * 128 + nt * 16 + m] = __float2half(acc[nt][i]);
            }
        }

        // fused attention dots: per-lane partials, butterfly over the 16 cols
        if (H == 4) {
            float ph[4][4], pdv[4][4];
#pragma unroll
            for (int h = 0; h < 4; h++)
#pragma unroll
                for (int i = 0; i < 4; i++) {
                    ph[h][i]  = acc[2 * h][i] * atts_v[2 * h] + acc[2 * h + 1][i] * atts_v[2 * h + 1];
                    pdv[h][i] = acc[2 * h][i] * attd_v[2 * h] + acc[2 * h + 1][i] * attd_v[2 * h + 1];
                }
#pragma unroll
            for (int lvl = 0; lvl < 4; lvl++) {
                const int msk = 1 << lvl;
#pragma unroll
                for (int h = 0; h < 4; h++)
#pragma unroll
                    for (int i = 0; i < 4; i++) {
                        ph[h][i]  += __shfl_xor(ph[h][i], msk, 64);
                        pdv[h][i] += __shfl_xor(pdv[h][i], msk, 64);
                    }
            }
            if (m == 0) {
#pragma unroll
                for (int i = 0; i < 4; i++) {
                    int r = rowb + q * 4 + i;
                    if (r < N) {
#pragma unroll
                        for (int h = 0; h < 4; h++) {
                            as_[(size_t)r * 4 + h] = ph[h][i];
                            ad_[(size_t)r * 4 + h] = pdv[h][i];
                        }
                    }
                }
            }
        } else {
            float ps[4], pdv[4];
#pragma unroll
            for (int i = 0; i < 4; i++) {
                float s = 0.f, dsum = 0.f;
#pragma unroll
                for (int nt = 0; nt < 8; nt++) {
                    s    += acc[nt][i] * atts_v[nt];
                    dsum += acc[nt][i] * attd_v[nt];
                }
                ps[i] = s; pdv[i] = dsum;
            }
#pragma unroll
            for (int lvl = 0; lvl < 4; lvl++) {
                const int msk = 1 << lvl;
#pragma unroll
                for (int i = 0; i < 4; i++) {
                    ps[i]  += __shfl_xor(ps[i], msk, 64);
                    pdv[i] += __shfl_xor(pdv[i], msk, 64);
                }
            }
            if (m == 0) {
#pragma unroll
                for (int i = 0; i < 4; i++) {
                    int r = rowb + q * 4 + i;
                    if (r < N) { as_[r] = ps[i]; ad_[r] = pdv[i]; }
                }
            }
        }
        __syncthreads();   // protect Xh before next tile's staging
    }
}

// ---------------- aggregation: one wave per dst node ----------------
// R12 form: 16 lanes per edge at 16B/lane; group g owns 4 CONSECUTIVE edges
// [b0+4g, b0+4g+4). Full batches read edge ids/alphas as int4/float4 from
// LDS (2 vector reads vs 8 scalar) and run unpredicated; tail batch (<16
// edges) predicated by zero weight. Cross-group reduce at node end.
// Cheap ELU epilogue (R11): __expf(r)-1.

template <int H, typename TO>
__global__ __launch_bounds__(256) void k_agg(
    const __half* __restrict__ feat,  // [N,128] fp16
    const float* __restrict__ asrc,   // [N,H]
    const float* __restrict__ adst,   // [N,H]
    const int*   __restrict__ off,    // [N+1]
    const int*   __restrict__ esrc,   // [E]
    const float* __restrict__ bias,   // [128]
    TO*          __restrict__ out,    // [N,128]
    int N)
{
    __shared__ __attribute__((aligned(16))) int   sj[4][64];
    __shared__ __attribute__((aligned(16))) float sp[4][64 * H];  // head-major

    int wave = threadIdx.x >> 6;
    int lane = threadIdx.x & 63;
    int node = (blockIdx.x * 256 + threadIdx.x) >> 6;
    if (node >= N) return;
    int beg = off[node], end = off[node + 1];

    float adst_i[H];
#pragma unroll
    for (int h = 0; h < H; h++) adst_i[h] = adst[(size_t)node * H + h];

    const int g    = lane >> 4;                    // edge sub-slot 0..3
    const int sub  = lane & 15;                    // col octet: cols sub*8..+7
    const int head = (H == 4) ? (sub >> 2) : 0;    // 32 cols per head
    const __half* fb = feat + sub * 8;

    float o[8];
#pragma unroll
    for (int k = 0; k < 8; k++) o[k] = 0.f;
    float ssum = 0.f;

    for (int cbeg = beg; cbeg < end; cbeg += 64) {
        int cnt = end - cbeg; if (cnt > 64) cnt = 64;
        if (lane < cnt) {
            int j = esrc[cbeg + lane];
            sj[wave][lane] = j;
            if (H == 4) {
                float4 av = *(const float4*)(asrc + (size_t)j * 4);
                float e;
                e = av.x + adst_i[0]; e = e > 0.f ? e : 0.2f * e; sp[wave][0 * 64 + lane] = __expf(e);
                e = av.y + adst_i[1]; e = e > 0.f ? e : 0.2f * e; sp[wave][1 * 64 + lane] = __expf(e);
                e = av.z + adst_i[2]; e = e > 0.f ? e : 0.2f * e; sp[wave][2 * 64 + lane] = __expf(e);
                e = av.w + adst_i[3]; e = e > 0.f ? e : 0.2f * e; sp[wave][3 * 64 + lane] = __expf(e);
            } else {
                float e = asrc[j] + adst_i[0];
                e = e > 0.f ? e : 0.2f * e;
                sp[wave][lane] = __expf(e);
            }
        }
        asm volatile("s_waitcnt lgkmcnt(0)" ::: "memory");

        const int fullc = cnt & ~15;
        // full batches: vector LDS reads, no predication
        for (int b0 = 0; b0 < fullc; b0 += 16) {
            int4   j4 = *(const int4*)  &sj[wave][b0 + 4 * g];
            float4 a4 = *(const float4*)&sp[wave][head * 64 + b0 + 4 * g];
            uint4 hv0 = *(const uint4*)(fb + (size_t)j4.x * 128);
            uint4 hv1 = *(const uint4*)(fb + (size_t)j4.y * 128);
            uint4 hv2 = *(const uint4*)(fb + (size_t)j4.z * 128);
            uint4 hv3 = *(const uint4*)(fb + (size_t)j4.w * 128);
            ssum += (a4.x + a4.y) + (a4.z + a4.w);
            const __half* h0 = (const __half*)&hv0;
            const __half* h1 = (const __half*)&hv1;
            const __half* h2 = (const __half*)&hv2;
            const __half* h3 = (const __half*)&hv3;
#pragma unroll
            for (int k = 0; k < 8; k++) {
                float v = fmaf(a4.x, __half2float(h0[k]), o[k]);
                v = fmaf(a4.y, __half2float(h1[k]), v);
                v = fmaf(a4.z, __half2float(h2[k]), v);
                o[k] = fmaf(a4.w, __half2float(h3[k]), v);
            }
        }
        // tail batch (<16 edges): predicated
        if (fullc < cnt) {
            float aa[4]; uint4 hv[4];
#pragma unroll
            for (int u = 0; u < 4; u++) {
                int e  = fullc + 4 * g + u;
                bool ok = e < cnt;
                int ec = ok ? e : fullc;
                int j  = sj[wave][ec];
                aa[u]  = ok ? sp[wave][head * 64 + ec] : 0.f;
                hv[u]  = *(const uint4*)(fb + (size_t)j * 128);
            }
#pragma unroll
            for (int u = 0; u < 4; u++) {
                const __half* hp = (const __half*)&hv[u];
                ssum += aa[u];
#pragma unroll
                for (int k = 0; k < 8; k++)
                    o[k] = fmaf(aa[u], __half2float(hp[k]), o[k]);
            }
        }
        // same-wave lockstep: staging of the next chunk cannot race these reads
    }

    // reduce across the 4 edge-groups (lanes with equal sub share cols/head)
#pragma unroll
    for (int k = 0; k < 8; k++) {
        o[k] += __shfl_xor(o[k], 16, 64);
        o[k] += __shfl_xor(o[k], 32, 64);
    }
    ssum += __shfl_xor(ssum, 16, 64);
    ssum += __shfl_xor(ssum, 32, 64);

    if (g == 0) {
        float inv = 1.f / (ssum + 1e-16f);
        float r[8];
#pragma unroll
        for (int k = 0; k < 8; k++) {
            r[k] = o[k] * inv + bias[sub * 8 + k];
            float er = __expf(r[k]) - 1.0f;          // cheap ELU branch (abs err ~1e-6)
            r[k] = r[k] > 0.f ? r[k] : er;
        }
        if constexpr (sizeof(TO) == 2) {
            __half2 hh[4];
#pragma unroll
            for (int p = 0; p < 4; p++) hh[p] = __floats2half2_rn(r[2 * p], r[2 * p + 1]);
            *(uint4*)((__half*)out + (size_t)node * 128 + sub * 8) = *(const uint4*)hh;
        } else {
            float4 v0 = make_float4(r[0], r[1], r[2], r[3]);
            float4 v1 = make_float4(r[4], r[5], r[6], r[7]);
            *(float4*)((float*)out + (size_t)node * 128 + sub * 8)     = v0;
            *(float4*)((float*)out + (size_t)node * 128 + sub * 8 + 4) = v1;
        }
    }
}

// ---------------- launch ----------------

extern "C" void kernel_launch(void* const* d_in, const int* in_sizes, int n_in,
                              void* d_out, int out_size, void* d_ws, size_t ws_size,
                              hipStream_t stream)
{
    const float* x    = (const float*)d_in[0];
    const int*   a    = (const int*)  d_in[1];
    const float* W1   = (const float*)d_in[2];
    const float* as1w = (const float*)d_in[3];
    const float* ad1w = (const float*)d_in[4];
    const float* b1   = (const float*)d_in[5];
    const float* W2   = (const float*)d_in[6];
    const float* as2w = (const float*)d_in[7];
    const float* ad2w = (const float*)d_in[8];
    const float* b2   = (const float*)d_in[9];

    const int N = in_sizes[0] / 128;
    const int E = in_sizes[1] / 2;
    const int* srcA = a;
    const int* dstA = a + E;
    const int NBUCK = (N + 127) >> 7;

    char* ws = (char*)d_ws;
    size_t o = 0;
    auto alloc = [&](size_t bytes) -> void* {
        void* p = ws + o;
        o += (bytes + 255) & ~(size_t)255;
        return p;
    };
    __half* hbuf  = (__half*)alloc((size_t)N * 128 * 2);  // fp16 gather payload
    __half* hact  = (__half*)alloc((size_t)N * 128 * 2);  // elu(gat1) fp16, GEMM2 input
    float*  as1   = (float*) alloc((size_t)N * 4 * 4);
    float*  ad1   = (float*) alloc((size_t)N * 4 * 4);
    float*  as2   = (float*) alloc((size_t)N * 4);
    float*  ad2   = (float*) alloc((size_t)N * 4);
    int*    off   = (int*)   alloc((size_t)(N + 1) * 4);
    int*    esrc  = (int*)   alloc((size_t)E * 4);
    int*    tmp   = (int*)   alloc((size_t)E * 4);
    int*    bcnt  = (int*)   alloc(1024 * 4);
    int*    bbase = (int*)   alloc(1025 * 4);
    int*    bcur  = (int*)   alloc(1024 * 4);

    // CSR build (rebuilt each launch; ws is re-poisoned)
    hipMemsetAsync(bcnt, 0, (size_t)NBUCK * 4, stream);
    k_hist<<<256, 256, 0, stream>>>(dstA, bcnt, E, NBUCK);
    k_bscan<<<1, 1024, 0, stream>>>(bcnt, bbase, bcur, off, NBUCK, N, E);
    k_binscatter<<<(E + 8191) / 8192, 256, 0, stream>>>(srcA, dstA, bcur, tmp, E, NBUCK);
    k_bsort<<<NBUCK, 256, 0, stream>>>(tmp, bbase, off, esrc, N);

    // layer 1 (MFMA GEMM + fused attdot, fp16 Y)
    k_gemm_mfma<4, float><<<768, 256, 0, stream>>>(x, W1, as1w, ad1w, hbuf, as1, ad1, N);
    k_agg<4, __half><<<(N + 3) / 4, 256, 0, stream>>>(hbuf, as1, ad1, off, esrc, b1, hact, N);

    // layer 2
    k_gemm_mfma<1, __half><<<768, 256, 0, stream>>>(hact, W2, as2w, ad2w, hbuf, as2, ad2, N);
    k_agg<1, float><<<(N + 3) / 4, 256, 0, stream>>>(hbuf, as2, ad2, off, esrc, b2, (float*)d_out, N);
}